// Round 2
// baseline (1105.246 us; speedup 1.0000x reference)
//
#include <hip/hip_runtime.h>
#include <hip/hip_bf16.h>

#define N_NODES 50000
#define N_EDGES 1600000
#define IN_CH 64
#define EDGE_DIM 32
#define ZDIM 160
#define NUM_HID 256
#define NUM_CLASSES 16
#define NUM_GRAPHS 512

typedef short bf16x8 __attribute__((ext_vector_type(8)));
typedef float f32x4 __attribute__((ext_vector_type(4)));

__device__ inline unsigned short f2b(float f) {
    unsigned int u = __float_as_uint(f);
    unsigned int r = (u + 0x7FFF + ((u >> 16) & 1)) >> 16;
    return (unsigned short)r;
}

__device__ inline void store4(unsigned short* p, float4 v) {
    ushort4 u;
    u.x = f2b(v.x); u.y = f2b(v.y); u.z = f2b(v.z); u.w = f2b(v.w);
    *(ushort4*)p = u;
}

// ---------------- degree ----------------
__global__ void deg_kernel(const int* __restrict__ ei, float* __restrict__ deg) {
    int i = blockIdx.x * 256 + threadIdx.x;
    if (i < N_EDGES) atomicAdd(&deg[ei[N_EDGES + i]], 1.0f);
}

// ---------------- edge GEMM + activation + scatter ----------------
// Per block: stage W_f,W_s (bf16) once; loop 64-edge tiles: gather Z -> LDS bf16,
// 4 waves x (32 edges x 32 msg-ch, both F and S), mfma 16x16x32, epilogue atomics.
__global__ __launch_bounds__(256, 2)
void edge_kernel(const float* __restrict__ xin, const int* __restrict__ ei,
                 const float* __restrict__ ea,
                 const float* __restrict__ wfv, const float* __restrict__ bfv,
                 const float* __restrict__ wsv, const float* __restrict__ bsv,
                 float* __restrict__ agg)
{
    __shared__ unsigned short Wl[128][168];  // rows 0..63 = W_f, 64..127 = W_s, [c][k]
    __shared__ unsigned short Zl[64][168];   // [edge][k]  k: 0..63 x[dst], 64..127 x[src], 128..159 ea
    __shared__ int dstl[64];
    const int tid = threadIdx.x;

    // stage weights (f32 -> bf16)
    {
        int r = tid >> 1, hh = tid & 1;
        const float* wrow = (r < 64) ? (wfv + r * 160) : (wsv + (r - 64) * 160);
        const float4* w4 = (const float4*)wrow;
        #pragma unroll
        for (int j = 0; j < 20; ++j) {
            float4 v = w4[hh * 20 + j];
            store4(&Wl[r][hh * 80 + j * 4], v);
        }
    }

    const int w = tid >> 6, lane = tid & 63;
    const int eh = (w >> 1) * 32;    // edge-half offset within tile
    const int chh = (w & 1) * 32;    // channel-half offset
    const int lr = lane & 15, lq = lane >> 4;

    float biasF[2], biasS[2];
    #pragma unroll
    for (int n = 0; n < 2; ++n) {
        biasF[n] = bfv[chh + n * 16 + lr];
        biasS[n] = bsv[chh + n * 16 + lr];
    }

    const int NT = N_EDGES / 64;
    for (int tile = blockIdx.x; tile < NT; tile += gridDim.x) {
        const int e0 = tile * 64;
        // ---- stage Z ----
        {
            int e = tid >> 2, q = tid & 3;
            int dst = ei[N_EDGES + e0 + e];
            int src = ei[e0 + e];
            if (q == 0) dstl[e] = dst;
            const float4* xd = (const float4*)(xin + (size_t)dst * 64 + q * 16);
            #pragma unroll
            for (int j = 0; j < 4; ++j) store4(&Zl[e][q * 16 + j * 4], xd[j]);
            const float4* xs = (const float4*)(xin + (size_t)src * 64 + q * 16);
            #pragma unroll
            for (int j = 0; j < 4; ++j) store4(&Zl[e][64 + q * 16 + j * 4], xs[j]);
            const float4* ae = (const float4*)(ea + (size_t)(e0 + e) * 32 + q * 8);
            #pragma unroll
            for (int j = 0; j < 2; ++j) store4(&Zl[e][128 + q * 8 + j * 4], ae[j]);
        }
        __syncthreads();

        // ---- MFMA ----
        f32x4 accF[2][2] = {}; f32x4 accS[2][2] = {};
        for (int ks = 0; ks < 5; ++ks) {
            const int k0 = ks * 32 + lq * 8;
            bf16x8 a0  = *(const bf16x8*)&Zl[eh + lr][k0];
            bf16x8 a1  = *(const bf16x8*)&Zl[eh + 16 + lr][k0];
            bf16x8 bF0 = *(const bf16x8*)&Wl[chh + lr][k0];
            bf16x8 bF1 = *(const bf16x8*)&Wl[chh + 16 + lr][k0];
            bf16x8 bS0 = *(const bf16x8*)&Wl[64 + chh + lr][k0];
            bf16x8 bS1 = *(const bf16x8*)&Wl[64 + chh + 16 + lr][k0];
            accF[0][0] = __builtin_amdgcn_mfma_f32_16x16x32_bf16(a0, bF0, accF[0][0], 0, 0, 0);
            accF[0][1] = __builtin_amdgcn_mfma_f32_16x16x32_bf16(a0, bF1, accF[0][1], 0, 0, 0);
            accF[1][0] = __builtin_amdgcn_mfma_f32_16x16x32_bf16(a1, bF0, accF[1][0], 0, 0, 0);
            accF[1][1] = __builtin_amdgcn_mfma_f32_16x16x32_bf16(a1, bF1, accF[1][1], 0, 0, 0);
            accS[0][0] = __builtin_amdgcn_mfma_f32_16x16x32_bf16(a0, bS0, accS[0][0], 0, 0, 0);
            accS[0][1] = __builtin_amdgcn_mfma_f32_16x16x32_bf16(a0, bS1, accS[0][1], 0, 0, 0);
            accS[1][0] = __builtin_amdgcn_mfma_f32_16x16x32_bf16(a1, bS0, accS[1][0], 0, 0, 0);
            accS[1][1] = __builtin_amdgcn_mfma_f32_16x16x32_bf16(a1, bS1, accS[1][1], 0, 0, 0);
        }

        // ---- epilogue: activations + atomic scatter ----
        #pragma unroll
        for (int m = 0; m < 2; ++m)
        #pragma unroll
        for (int n = 0; n < 2; ++n)
        #pragma unroll
        for (int i = 0; i < 4; ++i) {
            int e = eh + m * 16 + lq * 4 + i;
            int c = chh + n * 16 + lr;
            float f = accF[m][n][i] + biasF[n];
            float s = accS[m][n][i] + biasS[n];
            float sig = 1.0f / (1.0f + __expf(-f));
            float sp  = fmaxf(s, 0.0f) + log1pf(__expf(-fabsf(s)));
            atomicAdd(&agg[(size_t)dstl[e] * 64 + c], sig * sp);
        }
        __syncthreads();
    }
}

// ---------------- residual: h = agg/deg + x ----------------
__global__ void resid_kernel(const float4* __restrict__ agg, const float* __restrict__ deg,
                             const float4* __restrict__ x, float4* __restrict__ h)
{
    int i = blockIdx.x * 256 + threadIdx.x;
    if (i >= N_NODES * 16) return;
    int n = i >> 4;
    float inv = 1.0f / fmaxf(deg[n], 1.0f);
    float4 a = agg[i], xv = x[i];
    float4 r;
    r.x = a.x * inv + xv.x; r.y = a.y * inv + xv.y;
    r.z = a.z * inv + xv.z; r.w = a.w * inv + xv.w;
    h[i] = r;
}

// ---------------- layer-2 residual fused with graph pooling ----------------
__global__ void pool_kernel(const float4* __restrict__ agg, const float* __restrict__ deg,
                            const float4* __restrict__ h, const int* __restrict__ batch,
                            float* __restrict__ gsum)
{
    int i = blockIdx.x * 256 + threadIdx.x;
    if (i >= N_NODES * 16) return;
    int n = i >> 4;
    int g = batch[n];
    float inv = 1.0f / fmaxf(deg[n], 1.0f);
    float4 a = agg[i], hv = h[i];
    int base = g * 64 + (i & 15) * 4;
    atomicAdd(&gsum[base + 0], a.x * inv + hv.x);
    atomicAdd(&gsum[base + 1], a.y * inv + hv.y);
    atomicAdd(&gsum[base + 2], a.z * inv + hv.z);
    atomicAdd(&gsum[base + 3], a.w * inv + hv.w);
}

__global__ void gcnt_kernel(const int* __restrict__ batch, float* __restrict__ gcnt) {
    int i = blockIdx.x * 256 + threadIdx.x;
    if (i < N_NODES) atomicAdd(&gcnt[batch[i]], 1.0f);
}

// ---------------- head: MLP + log_softmax ----------------
__global__ __launch_bounds__(64)
void head_kernel(const float* __restrict__ gsum, const float* __restrict__ gcnt,
                 const float* __restrict__ w1, const float* __restrict__ b1,
                 const float* __restrict__ w2, const float* __restrict__ b2,
                 float* __restrict__ out)
{
    __shared__ float gv[64];
    __shared__ float hid[256];
    __shared__ float outv[16];
    const int g = blockIdx.x, t = threadIdx.x;
    float cnt = fmaxf(gcnt[g], 1.0f);
    gv[t] = gsum[g * 64 + t] / cnt;
    __syncthreads();
    #pragma unroll
    for (int r = 0; r < 4; ++r) {
        int c = t + r * 64;
        float acc = b1[c];
        const float4* wr = (const float4*)(w1 + c * 64);
        const float4* gvv = (const float4*)gv;
        #pragma unroll
        for (int k = 0; k < 16; ++k) {
            float4 wv = wr[k], xv = gvv[k];
            acc += wv.x * xv.x + wv.y * xv.y + wv.z * xv.z + wv.w * xv.w;
        }
        hid[c] = fmaxf(acc, 0.0f);
    }
    __syncthreads();
    if (t < 16) {
        float acc = b2[t];
        const float4* wr = (const float4*)(w2 + t * 256);
        const float4* hv = (const float4*)hid;
        for (int k = 0; k < 64; ++k) {
            float4 wv = wr[k], xv = hv[k];
            acc += wv.x * xv.x + wv.y * xv.y + wv.z * xv.z + wv.w * xv.w;
        }
        outv[t] = acc;
    }
    __syncthreads();
    if (t < 16) {
        float m = outv[0];
        #pragma unroll
        for (int j = 1; j < 16; ++j) m = fmaxf(m, outv[j]);
        float ssum = 0.0f;
        #pragma unroll
        for (int j = 0; j < 16; ++j) ssum += expf(outv[j] - m);
        out[g * 16 + t] = outv[t] - m - logf(ssum);
    }
}

extern "C" void kernel_launch(void* const* d_in, const int* in_sizes, int n_in,
                              void* d_out, int out_size, void* d_ws, size_t ws_size,
                              hipStream_t stream)
{
    const float* x    = (const float*)d_in[0];
    const int*   ei   = (const int*)d_in[1];
    const float* ea   = (const float*)d_in[2];
    const int*   batch= (const int*)d_in[3];
    const float* wf1  = (const float*)d_in[4];
    const float* bf1  = (const float*)d_in[5];
    const float* ws1  = (const float*)d_in[6];
    const float* bs1  = (const float*)d_in[7];
    const float* wf2  = (const float*)d_in[8];
    const float* bf2  = (const float*)d_in[9];
    const float* ws2  = (const float*)d_in[10];
    const float* bs2  = (const float*)d_in[11];
    const float* w1   = (const float*)d_in[12];
    const float* b1   = (const float*)d_in[13];
    const float* w2   = (const float*)d_in[14];
    const float* b2   = (const float*)d_in[15];
    float* out = (float*)d_out;

    char* ws = (char*)d_ws;
    float* deg  = (float*)(ws + 0);         // 200000 B
    float* agg  = (float*)(ws + 204800);    // 12.8 MB
    float* h    = (float*)(ws + 13004800);  // 12.8 MB
    float* gsum = (float*)(ws + 25804800);  // 131072 B
    float* gcnt = (float*)(ws + 25935872);  // 2048 B

    hipMemsetAsync(deg, 0, 200000, stream);
    hipMemsetAsync(agg, 0, 12800000, stream);
    hipMemsetAsync(gsum, 0, 131072 + 2048, stream);

    deg_kernel<<<(N_EDGES + 255) / 256, 256, 0, stream>>>(ei, deg);
    edge_kernel<<<512, 256, 0, stream>>>(x, ei, ea, wf1, bf1, ws1, bs1, agg);
    resid_kernel<<<(N_NODES * 16 + 255) / 256, 256, 0, stream>>>(
        (const float4*)agg, deg, (const float4*)x, (float4*)h);
    hipMemsetAsync(agg, 0, 12800000, stream);
    edge_kernel<<<512, 256, 0, stream>>>(h, ei, ea, wf2, bf2, ws2, bs2, agg);
    pool_kernel<<<(N_NODES * 16 + 255) / 256, 256, 0, stream>>>(
        (const float4*)agg, deg, (const float4*)h, batch, gsum);
    gcnt_kernel<<<(N_NODES + 255) / 256, 256, 0, stream>>>(batch, gcnt);
    head_kernel<<<NUM_GRAPHS, 64, 0, stream>>>(gsum, gcnt, w1, b1, w2, b2, out);
}

// Round 4
// 819.779 us; speedup vs baseline: 1.3482x; 1.3482x over previous
//
#include <hip/hip_runtime.h>
#include <hip/hip_bf16.h>

#define N_NODES 50000
#define N_EDGES 1600000
#define IN_CH 64
#define NUM_HID 256
#define NUM_CLASSES 16
#define NUM_GRAPHS 512

typedef short bf16x8 __attribute__((ext_vector_type(8)));
typedef float f32x4 __attribute__((ext_vector_type(4)));

#if __has_builtin(__builtin_amdgcn_rcpf)
#define RCPF(x) __builtin_amdgcn_rcpf(x)
#else
#define RCPF(x) (1.0f / (x))
#endif

__device__ inline unsigned short f2b(float f) {
    unsigned int u = __float_as_uint(f);
    unsigned int r = (u + 0x7FFF + ((u >> 16) & 1)) >> 16;
    return (unsigned short)r;
}

// ---------------- preprocessing ----------------
__global__ void prep_w_kernel(const float* __restrict__ wf1, const float* __restrict__ ws1,
                              const float* __restrict__ wf2, const float* __restrict__ ws2,
                              unsigned short* __restrict__ wb1, unsigned short* __restrict__ wb2) {
    int i = blockIdx.x * 256 + threadIdx.x;
    if (i >= 128 * 160) return;
    int r = i / 160, k = i - r * 160;
    wb1[i] = f2b(r < 64 ? wf1[r * 160 + k] : ws1[(r - 64) * 160 + k]);
    wb2[i] = f2b(r < 64 ? wf2[r * 160 + k] : ws2[(r - 64) * 160 + k]);
}

__global__ void prep_x_kernel(const float4* __restrict__ x, unsigned short* __restrict__ xb) {
    int i = blockIdx.x * 256 + threadIdx.x;
    if (i >= N_NODES * 16) return;
    float4 v = x[i];
    ushort4 u; u.x = f2b(v.x); u.y = f2b(v.y); u.z = f2b(v.z); u.w = f2b(v.w);
    *(ushort4*)(xb + i * 4) = u;
}

__global__ void hist_kernel(const int* __restrict__ ei, int* __restrict__ cnt) {
    int i = blockIdx.x * 256 + threadIdx.x;
    if (i < N_EDGES) atomicAdd(&cnt[ei[N_EDGES + i]], 1);
}

__global__ __launch_bounds__(1024)
void scan_kernel(const int* __restrict__ cnt, int* __restrict__ cursor, float* __restrict__ inv_deg) {
    __shared__ int part[1024];
    const int t = threadIdx.x;
    const int PER = (N_NODES + 1023) / 1024;  // 49
    int base = t * PER;
    int s = 0;
    for (int j = 0; j < PER; ++j) { int idx = base + j; if (idx < N_NODES) s += cnt[idx]; }
    part[t] = s; __syncthreads();
    for (int off = 1; off < 1024; off <<= 1) {
        int v = (t >= off) ? part[t - off] : 0;
        __syncthreads();
        part[t] += v;
        __syncthreads();
    }
    int run = (t == 0) ? 0 : part[t - 1];
    for (int j = 0; j < PER; ++j) {
        int idx = base + j;
        if (idx < N_NODES) {
            cursor[idx] = run;
            int c = cnt[idx];
            run += c;
            inv_deg[idx] = 1.0f / fmaxf((float)c, 1.0f);
        }
    }
}

__global__ void scatter_kernel(const int* __restrict__ ei, int* __restrict__ cursor,
                               int* __restrict__ ssrc, int* __restrict__ sdst, int* __restrict__ eid) {
    int e = blockIdx.x * 256 + threadIdx.x;
    if (e >= N_EDGES) return;
    int d = ei[N_EDGES + e];
    int p = atomicAdd(&cursor[d], 1);
    ssrc[p] = ei[e];
    sdst[p] = d;
    eid[p] = e;
}

// ---------------- edge pass: gather -> MFMA -> activation -> run-reduced scatter ----------------
// Edges sorted by dst. 64-edge tiles, 4 waves: wave quadrant (eh,chh). B (both weight
// matrices) held in registers. Z staged in packed LDS with chunk-XOR swizzle.
__global__ __launch_bounds__(256, 2)
void edge_mfma(const unsigned short* __restrict__ xb,
               const int* __restrict__ ssrc, const int* __restrict__ sdst,
               const int* __restrict__ eid, const float* __restrict__ ea,
               const unsigned short* __restrict__ wb,
               const float* __restrict__ bfv, const float* __restrict__ bsv,
               float* __restrict__ agg)
{
    __shared__ __align__(16) unsigned short Zd[64 * 64];  // [e][8 chunks], chunk c holds data chunk c^(e&7)
    __shared__ __align__(16) unsigned short Zs[64 * 64];
    __shared__ __align__(16) unsigned short Ze[64 * 32];  // chunk c holds data chunk c^((e>>1)&3)
    __shared__ float msg[64 * 65];
    __shared__ int dstl[2][64];

    const int tid = threadIdx.x;
    const int w = tid >> 6, lane = tid & 63, lr = lane & 15, lq = lane >> 4;
    const int eh = (w >> 1) * 32, chh = (w & 1) * 32;

    // B fragments (gate mat=0, filter mat=1) in registers: 20 x 16B
    bf16x8 B[2][2][5];
    #pragma unroll
    for (int mat = 0; mat < 2; ++mat)
        #pragma unroll
        for (int n = 0; n < 2; ++n)
            #pragma unroll
            for (int ks = 0; ks < 5; ++ks)
                B[mat][n][ks] = *(const bf16x8*)(wb + (size_t)(mat * 64 + chh + n * 16 + lr) * 160 + ks * 32 + lq * 8);

    float biasF[2], biasS[2];
    #pragma unroll
    for (int n = 0; n < 2; ++n) { biasF[n] = bfv[chh + n * 16 + lr]; biasS[n] = bsv[chh + n * 16 + lr]; }

    // staging roles: Zd/Zs chunks tid and tid+256; Ze chunk tid
    const int rA0 = tid >> 3, cA0 = tid & 7;
    const int rA1 = rA0 + 32;
    const int rE = tid >> 2, cE = tid & 3;
    const int dcA0 = cA0 ^ (rA0 & 7), dcA1 = cA0 ^ (rA1 & 7);
    const int dcE = cE ^ ((rE >> 1) & 3);

    const int NT = N_EDGES / 64;
    const int nblk = gridDim.x;

    bf16x8 vd0, vd1, vs0, vs1;
    float4 ve0, ve1;
    int dl = 0;

    #define ISSUE(T) do { \
        int e0_ = (T) * 64; \
        int nd0 = sdst[e0_ + rA0], nd1 = sdst[e0_ + rA1]; \
        int ns0 = ssrc[e0_ + rA0], ns1 = ssrc[e0_ + rA1]; \
        int ide = eid[e0_ + rE]; \
        vd0 = *(const bf16x8*)(xb + (size_t)nd0 * 64 + dcA0 * 8); \
        vd1 = *(const bf16x8*)(xb + (size_t)nd1 * 64 + dcA1 * 8); \
        vs0 = *(const bf16x8*)(xb + (size_t)ns0 * 64 + dcA0 * 8); \
        vs1 = *(const bf16x8*)(xb + (size_t)ns1 * 64 + dcA1 * 8); \
        ve0 = *(const float4*)(ea + (size_t)ide * 32 + dcE * 8); \
        ve1 = *(const float4*)(ea + (size_t)ide * 32 + dcE * 8 + 4); \
        if (tid < 64) dl = sdst[e0_ + tid]; \
    } while (0)

    #define WRITE(PAR) do { \
        *(bf16x8*)&Zd[rA0 * 64 + cA0 * 8] = vd0; \
        *(bf16x8*)&Zd[rA1 * 64 + cA0 * 8] = vd1; \
        *(bf16x8*)&Zs[rA0 * 64 + cA0 * 8] = vs0; \
        *(bf16x8*)&Zs[rA1 * 64 + cA0 * 8] = vs1; \
        ushort4 ua, ub; \
        ua.x = f2b(ve0.x); ua.y = f2b(ve0.y); ua.z = f2b(ve0.z); ua.w = f2b(ve0.w); \
        ub.x = f2b(ve1.x); ub.y = f2b(ve1.y); ub.z = f2b(ve1.z); ub.w = f2b(ve1.w); \
        *(ushort4*)&Ze[rE * 32 + cE * 8] = ua; \
        *(ushort4*)&Ze[rE * 32 + cE * 8 + 4] = ub; \
        if (tid < 64) dstl[PAR][tid] = dl; \
    } while (0)

    int t = blockIdx.x;
    if (t < NT) { ISSUE(t); WRITE(0); }
    __syncthreads();
    int par = 0;

    for (; t < NT; t += nblk) {
        int tn = t + nblk;
        bool pf = tn < NT;
        if (pf) ISSUE(tn);

        // ---- k-loop ----
        f32x4 aF[2][2] = {}; f32x4 aS[2][2] = {};
        const int r0 = eh + lr, r1 = eh + 16 + lr;
        #pragma unroll
        for (int ks = 0; ks < 5; ++ks) {
            bf16x8 a0, a1;
            if (ks < 2) {
                int j = ks * 4 + lq;
                a0 = *(const bf16x8*)&Zd[r0 * 64 + ((j ^ (r0 & 7)) * 8)];
                a1 = *(const bf16x8*)&Zd[r1 * 64 + ((j ^ (r1 & 7)) * 8)];
            } else if (ks < 4) {
                int j = (ks - 2) * 4 + lq;
                a0 = *(const bf16x8*)&Zs[r0 * 64 + ((j ^ (r0 & 7)) * 8)];
                a1 = *(const bf16x8*)&Zs[r1 * 64 + ((j ^ (r1 & 7)) * 8)];
            } else {
                a0 = *(const bf16x8*)&Ze[r0 * 32 + ((lq ^ ((r0 >> 1) & 3)) * 8)];
                a1 = *(const bf16x8*)&Ze[r1 * 32 + ((lq ^ ((r1 >> 1) & 3)) * 8)];
            }
            aF[0][0] = __builtin_amdgcn_mfma_f32_16x16x32_bf16(a0, B[0][0][ks], aF[0][0], 0, 0, 0);
            aF[0][1] = __builtin_amdgcn_mfma_f32_16x16x32_bf16(a0, B[0][1][ks], aF[0][1], 0, 0, 0);
            aF[1][0] = __builtin_amdgcn_mfma_f32_16x16x32_bf16(a1, B[0][0][ks], aF[1][0], 0, 0, 0);
            aF[1][1] = __builtin_amdgcn_mfma_f32_16x16x32_bf16(a1, B[0][1][ks], aF[1][1], 0, 0, 0);
            aS[0][0] = __builtin_amdgcn_mfma_f32_16x16x32_bf16(a0, B[1][0][ks], aS[0][0], 0, 0, 0);
            aS[0][1] = __builtin_amdgcn_mfma_f32_16x16x32_bf16(a0, B[1][1][ks], aS[0][1], 0, 0, 0);
            aS[1][0] = __builtin_amdgcn_mfma_f32_16x16x32_bf16(a1, B[1][0][ks], aS[1][0], 0, 0, 0);
            aS[1][1] = __builtin_amdgcn_mfma_f32_16x16x32_bf16(a1, B[1][1][ks], aS[1][1], 0, 0, 0);
        }
        __syncthreads();  // B2: all waves done with Z reads and previous msg reads

        // ---- activation -> msg ----
        #pragma unroll
        for (int m = 0; m < 2; ++m)
            #pragma unroll
            for (int n = 0; n < 2; ++n)
                #pragma unroll
                for (int i = 0; i < 4; ++i) {
                    int e = eh + m * 16 + lq * 4 + i;
                    int c = chh + n * 16 + lr;
                    float f = aF[m][n][i] + biasF[n];
                    float s = aS[m][n][i] + biasS[n];
                    float sig = RCPF(1.0f + __expf(-f));
                    float sp = fmaxf(s, 0.0f) + __logf(1.0f + __expf(-fabsf(s)));
                    msg[e * 65 + c] = sig * sp;
                }
        __syncthreads();  // B3

        // ---- run-reduction: wave w owns edges [w*16, w*16+16), channel = lane ----
        {
            float acc = 0.0f;
            int dcur = dstl[par][w * 16];
            #pragma unroll
            for (int j = 0; j < 16; ++j) {
                int e = w * 16 + j;
                int d = dstl[par][e];           // wave-uniform
                float v = msg[e * 65 + lane];
                if (d != dcur) {
                    atomicAdd(&agg[(size_t)dcur * 64 + lane], acc);
                    dcur = d; acc = v;
                } else {
                    acc += v;
                }
            }
            atomicAdd(&agg[(size_t)dcur * 64 + lane], acc);
        }

        if (pf) WRITE(par ^ 1);
        __syncthreads();  // B1: staged tile visible; separates reduce from next msg-write
        par ^= 1;
    }
    #undef ISSUE
    #undef WRITE
}

// ---------------- residual: h = agg*inv_deg + x ; also bf16 copy ----------------
__global__ void resid2_kernel(const float4* __restrict__ agg, const float* __restrict__ inv_deg,
                              const float4* __restrict__ x, float4* __restrict__ h,
                              unsigned short* __restrict__ hb)
{
    int i = blockIdx.x * 256 + threadIdx.x;
    if (i >= N_NODES * 16) return;
    int n = i >> 4;
    float iv = inv_deg[n];
    float4 a = agg[i], xv = x[i], r;
    r.x = a.x * iv + xv.x; r.y = a.y * iv + xv.y;
    r.z = a.z * iv + xv.z; r.w = a.w * iv + xv.w;
    h[i] = r;
    ushort4 u; u.x = f2b(r.x); u.y = f2b(r.y); u.z = f2b(r.z); u.w = f2b(r.w);
    *(ushort4*)(hb + i * 4) = u;
}

// ---------------- layer-2 residual fused with graph pooling ----------------
__global__ void pool2_kernel(const float4* __restrict__ agg, const float* __restrict__ inv_deg,
                             const float4* __restrict__ h, const int* __restrict__ batch,
                             float* __restrict__ gsum)
{
    int i = blockIdx.x * 256 + threadIdx.x;
    if (i >= N_NODES * 16) return;
    int n = i >> 4;
    int g = batch[n];
    float iv = inv_deg[n];
    float4 a = agg[i], hv = h[i];
    int base = g * 64 + (i & 15) * 4;
    atomicAdd(&gsum[base + 0], a.x * iv + hv.x);
    atomicAdd(&gsum[base + 1], a.y * iv + hv.y);
    atomicAdd(&gsum[base + 2], a.z * iv + hv.z);
    atomicAdd(&gsum[base + 3], a.w * iv + hv.w);
}

__global__ void gcnt_kernel(const int* __restrict__ batch, float* __restrict__ gcnt) {
    int i = blockIdx.x * 256 + threadIdx.x;
    if (i < N_NODES) atomicAdd(&gcnt[batch[i]], 1.0f);
}

// ---------------- head: MLP + log_softmax ----------------
__global__ __launch_bounds__(64)
void head_kernel(const float* __restrict__ gsum, const float* __restrict__ gcnt,
                 const float* __restrict__ w1, const float* __restrict__ b1,
                 const float* __restrict__ w2, const float* __restrict__ b2,
                 float* __restrict__ out)
{
    __shared__ float gv[64];
    __shared__ float hid[256];
    __shared__ float outv[16];
    const int g = blockIdx.x, t = threadIdx.x;
    float cnt = fmaxf(gcnt[g], 1.0f);
    gv[t] = gsum[g * 64 + t] / cnt;
    __syncthreads();
    #pragma unroll
    for (int r = 0; r < 4; ++r) {
        int c = t + r * 64;
        float acc = b1[c];
        const float4* wr = (const float4*)(w1 + c * 64);
        const float4* gvv = (const float4*)gv;
        #pragma unroll
        for (int k = 0; k < 16; ++k) {
            float4 wv = wr[k], xv = gvv[k];
            acc += wv.x * xv.x + wv.y * xv.y + wv.z * xv.z + wv.w * xv.w;
        }
        hid[c] = fmaxf(acc, 0.0f);
    }
    __syncthreads();
    if (t < 16) {
        float acc = b2[t];
        const float4* wr = (const float4*)(w2 + t * 256);
        const float4* hv = (const float4*)hid;
        for (int k = 0; k < 64; ++k) {
            float4 wv = wr[k], xv = hv[k];
            acc += wv.x * xv.x + wv.y * xv.y + wv.z * xv.z + wv.w * xv.w;
        }
        outv[t] = acc;
    }
    __syncthreads();
    if (t < 16) {
        float m = outv[0];
        #pragma unroll
        for (int j = 1; j < 16; ++j) m = fmaxf(m, outv[j]);
        float ssum = 0.0f;
        #pragma unroll
        for (int j = 0; j < 16; ++j) ssum += expf(outv[j] - m);
        out[g * 16 + t] = outv[t] - m - logf(ssum);
    }
}

extern "C" void kernel_launch(void* const* d_in, const int* in_sizes, int n_in,
                              void* d_out, int out_size, void* d_ws, size_t ws_size,
                              hipStream_t stream)
{
    const float* x     = (const float*)d_in[0];
    const int*   ei    = (const int*)d_in[1];
    const float* ea    = (const float*)d_in[2];
    const int*   batch = (const int*)d_in[3];
    const float* wf1 = (const float*)d_in[4];
    const float* bf1 = (const float*)d_in[5];
    const float* ws1 = (const float*)d_in[6];
    const float* bs1 = (const float*)d_in[7];
    const float* wf2 = (const float*)d_in[8];
    const float* bf2 = (const float*)d_in[9];
    const float* ws2 = (const float*)d_in[10];
    const float* bs2 = (const float*)d_in[11];
    const float* w1 = (const float*)d_in[12];
    const float* b1 = (const float*)d_in[13];
    const float* w2 = (const float*)d_in[14];
    const float* b2 = (const float*)d_in[15];
    float* out = (float*)d_out;

    char* ws = (char*)d_ws;
    int*   cnt    = (int*)(ws + 0x000000);           // 200 KB
    int*   cursor = (int*)(ws + 0x040000);           // 200 KB
    float* invdeg = (float*)(ws + 0x080000);         // 200 KB
    int*   eid    = (int*)(ws + 0x100000);           // 6.4 MB
    int*   ssrc   = (int*)(ws + 0x800000);           // 6.4 MB
    int*   sdst   = (int*)(ws + 0xF00000);           // 6.4 MB
    unsigned short* xb = (unsigned short*)(ws + 0x1600000);  // 6.4 MB
    unsigned short* hb = (unsigned short*)(ws + 0x1D00000);  // 6.4 MB
    float* agg = (float*)(ws + 0x2400000);           // 12.8 MB
    float* h   = (float*)(ws + 0x3200000);           // 12.8 MB
    unsigned short* wb1 = (unsigned short*)(ws + 0x4000000); // 40 KB
    unsigned short* wb2 = (unsigned short*)(ws + 0x4010000); // 40 KB
    float* gsum = (float*)(ws + 0x4020000);          // 128 KB
    float* gcnt = (float*)(ws + 0x4040000);          // 2 KB

    hipMemsetAsync(cnt, 0, 200000, stream);
    hipMemsetAsync(agg, 0, 12800000, stream);
    hipMemsetAsync(gsum, 0, 131072 + 2048, stream);

    prep_w_kernel<<<80, 256, 0, stream>>>(wf1, ws1, wf2, ws2, wb1, wb2);
    prep_x_kernel<<<3125, 256, 0, stream>>>((const float4*)x, xb);
    hist_kernel<<<6250, 256, 0, stream>>>(ei, cnt);
    scan_kernel<<<1, 1024, 0, stream>>>(cnt, cursor, invdeg);
    scatter_kernel<<<6250, 256, 0, stream>>>(ei, cursor, ssrc, sdst, eid);

    edge_mfma<<<512, 256, 0, stream>>>(xb, ssrc, sdst, eid, ea, wb1, bf1, bs1, agg);
    resid2_kernel<<<3125, 256, 0, stream>>>((const float4*)agg, invdeg, (const float4*)x,
                                            (float4*)h, hb);
    hipMemsetAsync(agg, 0, 12800000, stream);
    edge_mfma<<<512, 256, 0, stream>>>(hb, ssrc, sdst, eid, ea, wb2, bf2, bs2, agg);
    pool2_kernel<<<3125, 256, 0, stream>>>((const float4*)agg, invdeg, (const float4*)h,
                                           batch, gsum);
    gcnt_kernel<<<196, 256, 0, stream>>>(batch, gcnt);
    head_kernel<<<NUM_GRAPHS, 64, 0, stream>>>(gsum, gcnt, w1, b1, w2, b2, out);
}